// Round 3
// baseline (403.720 us; speedup 1.0000x reference)
//
#include <hip/hip_runtime.h>

using u16    = unsigned short;
using short8 = __attribute__((ext_vector_type(8))) short;
using u16x8  = __attribute__((ext_vector_type(8))) u16;
using u16x4  = __attribute__((ext_vector_type(4))) u16;
using f32x4  = __attribute__((ext_vector_type(4))) float;

#define M_DIM 8192   // B*S = 16*512
#define N_DIM 1024   // D_OUT
#define K_DIM 4096   // D_IN

typedef __attribute__((address_space(1))) void gvoid;
typedef __attribute__((address_space(3))) void svoid;
#define GLOAD_LDS16(g, s) \
  __builtin_amdgcn_global_load_lds((gvoid*)(void*)(g), (svoid*)(s), 16, 0, 0)

__device__ __forceinline__ u16 f2bf(float f) {
  unsigned u = __builtin_bit_cast(unsigned, f);
  u = (u + 0x7FFFu + ((u >> 16) & 1u)) >> 16;   // RNE
  return (u16)u;
}

// ---- kernel 1: per-row alpha = mean|W|, Wsgn = sign(W) as bf16 (+1/-1/0 exact)
__global__ __launch_bounds__(256) void wprep_kernel(const float* __restrict__ W,
                                                    u16* __restrict__ Wsgn,
                                                    float* __restrict__ alpha) {
  const int row = blockIdx.x;
  const int t   = threadIdx.x;
  const float4* wr = (const float4*)(W + (size_t)row * K_DIM);
  float4 v[4];
  float s = 0.f;
#pragma unroll
  for (int j = 0; j < 4; ++j) {
    v[j] = wr[t + 256 * j];
    s += fabsf(v[j].x) + fabsf(v[j].y) + fabsf(v[j].z) + fabsf(v[j].w);
  }
#pragma unroll
  for (int off = 32; off > 0; off >>= 1) s += __shfl_down(s, off, 64);
  __shared__ float red[4];
  if ((t & 63) == 0) red[t >> 6] = s;
  __syncthreads();
  if (t == 0) alpha[row] = (red[0] + red[1] + red[2] + red[3]) * (1.0f / K_DIM);
  u16x4* dst = (u16x4*)(Wsgn + (size_t)row * K_DIM);
#pragma unroll
  for (int j = 0; j < 4; ++j) {
    u16x4 sg;
    sg[0] = v[j].x > 0.f ? 0x3F80 : (v[j].x < 0.f ? 0xBF80 : 0);
    sg[1] = v[j].y > 0.f ? 0x3F80 : (v[j].y < 0.f ? 0xBF80 : 0);
    sg[2] = v[j].z > 0.f ? 0x3F80 : (v[j].z < 0.f ? 0xBF80 : 0);
    sg[3] = v[j].w > 0.f ? 0x3F80 : (v[j].w < 0.f ? 0xBF80 : 0);
    dst[t + 256 * j] = sg;
  }
}

// ---- kernel 2: GEMM C[m,n] = sum_k A[m,k]*Wsgn[n,k], epilogue *alpha + b + resid
// Round 3: 64x128 (MxN) tile -> 1024 blocks = 4 blocks/CU (TLP vs barrier drain);
// A converted fp32->bf16 inline during staging (cast kernel eliminated).
// LDS layout: row-major rows of 32 u16, k-group slot s holds global k-group
// s ^ (row&3) (XOR swizzle folded into source addr for global_load_lds).
__global__ __launch_bounds__(256, 4) void gemm_kernel(const float* __restrict__ A,
                                                      const u16* __restrict__ Bsgn,
                                                      const float* __restrict__ alpha,
                                                      const float* __restrict__ bias,
                                                      const float* __restrict__ resid,
                                                      float* __restrict__ out) {
  __shared__ u16 lA[64 * 32];    // 4 KB
  __shared__ u16 lB[128 * 32];   // 8 KB
  const int tid  = threadIdx.x;
  const int wave = tid >> 6;
  const int lane = tid & 63;
  const int quad = lane >> 4;
  const int l16  = lane & 15;
  const int wm   = (wave >> 1) * 32;   // wave's M offset within tile
  const int wn   = (wave & 1) * 64;    // wave's N offset within tile

  // XCD swizzle: 1024 blocks; xcd = b&7 owns M-bands [xcd*16, xcd*16+16),
  // each band paired with all 8 N-tiles -> A rows read once per XCD via L2.
  const int b    = blockIdx.x;
  const int xcd  = b & 7;
  const int l    = b >> 3;                       // 0..127
  const size_t m0 = (size_t)(xcd * 16 + (l >> 3)) * 64;
  const size_t n0 = (size_t)(l & 7) * 128;

  f32x4 acc[2][4] = {};

  // B staging (global_load_lds): wave w stages rows [w*32, w*32+32)
  const int b_r = lane >> 2;                         // row within 16-row chunk
  const int b_k = (((lane & 3) ^ (b_r & 3)) * 8);    // source XOR swizzle
  const u16* bsrc0 = Bsgn + (n0 + (size_t)wave * 32 + b_r) * K_DIM + b_k;
  const u16* bsrc1 = Bsgn + (n0 + (size_t)wave * 32 + 16 + b_r) * K_DIM + b_k;
  u16* bdst0 = lB + wave * 1024;
  u16* bdst1 = lB + wave * 1024 + 512;

  // A staging (fp32 -> bf16 inline): thread t handles row=t>>2, k-group g=t&3
  const int a_r = tid >> 2;          // 0..63
  const int a_g = tid & 3;
  const float* asrc = A + (m0 + a_r) * (size_t)K_DIM + a_g * 8;
  u16* adst = lA + a_r * 32 + ((a_g ^ (a_r & 3)) * 8);

  for (int k0 = 0; k0 < K_DIM; k0 += 32) {
    // fire-and-forget B DMA first
    GLOAD_LDS16(bsrc0 + k0, bdst0);
    GLOAD_LDS16(bsrc1 + k0, bdst1);
    // A: 8 floats -> 8 bf16 -> one ds_write_b128
    float4 f0 = ((const float4*)(asrc + k0))[0];
    float4 f1 = ((const float4*)(asrc + k0))[1];
    u16x8 p;
    p[0] = f2bf(f0.x); p[1] = f2bf(f0.y); p[2] = f2bf(f0.z); p[3] = f2bf(f0.w);
    p[4] = f2bf(f1.x); p[5] = f2bf(f1.y); p[6] = f2bf(f1.z); p[7] = f2bf(f1.w);
    *(u16x8*)adst = p;
    asm volatile("s_waitcnt vmcnt(0)" ::: "memory");   // drain B DMA
    __syncthreads();

    short8 af[2], bf[4];
#pragma unroll
    for (int mt = 0; mt < 2; ++mt) {
      const int row = wm + mt * 16 + l16;
      af[mt] = *(const short8*)(lA + row * 32 + ((quad ^ (l16 & 3)) * 8));
    }
#pragma unroll
    for (int nt = 0; nt < 4; ++nt) {
      const int col = wn + nt * 16 + l16;
      bf[nt] = *(const short8*)(lB + col * 32 + ((quad ^ (l16 & 3)) * 8));
    }
#pragma unroll
    for (int mt = 0; mt < 2; ++mt)
#pragma unroll
      for (int nt = 0; nt < 4; ++nt)
        acc[mt][nt] = __builtin_amdgcn_mfma_f32_16x16x32_bf16(af[mt], bf[nt],
                                                              acc[mt][nt], 0, 0, 0);
    __syncthreads();
  }

  // epilogue: x = acc*alpha[n] + b[n] + resid ; C/D map: col=l16, row=quad*4+r
#pragma unroll
  for (int nt = 0; nt < 4; ++nt) {
    const size_t n  = n0 + wn + nt * 16 + l16;
    const float  al = alpha[n];
    const float  bi = bias[n];
#pragma unroll
    for (int mt = 0; mt < 2; ++mt) {
      const size_t mbase = m0 + wm + mt * 16 + quad * 4;
#pragma unroll
      for (int r = 0; r < 4; ++r) {
        const size_t mm = mbase + r;
        out[mm * N_DIM + n] = acc[mt][nt][r] * al + bi + resid[mm * N_DIM + n];
      }
    }
  }
}

// ---- kernel 3: LayerNorm over last dim (1024), in-place on d_out
__global__ __launch_bounds__(256) void ln_kernel(float* __restrict__ x,
                                                 const float* __restrict__ gamma,
                                                 const float* __restrict__ beta) {
  const size_t row = blockIdx.x;
  float4* xr = (float4*)(x + row * N_DIM);
  const int t = threadIdx.x;
  float4 v = xr[t];
  float s  = v.x + v.y + v.z + v.w;
  float sq = v.x * v.x + v.y * v.y + v.z * v.z + v.w * v.w;
#pragma unroll
  for (int off = 32; off > 0; off >>= 1) {
    s  += __shfl_down(s, off, 64);
    sq += __shfl_down(sq, off, 64);
  }
  __shared__ float rs[4], rq[4];
  if ((t & 63) == 0) { rs[t >> 6] = s; rq[t >> 6] = sq; }
  __syncthreads();
  s  = rs[0] + rs[1] + rs[2] + rs[3];
  sq = rq[0] + rq[1] + rq[2] + rq[3];
  const float mu  = s * (1.0f / N_DIM);
  float var = sq * (1.0f / N_DIM) - mu * mu;
  var = fmaxf(var, 0.0f);
  const float inv = rsqrtf(var + 1e-12f);
  const float4 g = ((const float4*)gamma)[t];
  const float4 b = ((const float4*)beta)[t];
  v.x = g.x * ((v.x - mu) * inv) + b.x;
  v.y = g.y * ((v.y - mu) * inv) + b.y;
  v.z = g.z * ((v.z - mu) * inv) + b.z;
  v.w = g.w * ((v.w - mu) * inv) + b.w;
  xr[t] = v;
}

extern "C" void kernel_launch(void* const* d_in, const int* in_sizes, int n_in,
                              void* d_out, int out_size, void* d_ws, size_t ws_size,
                              hipStream_t stream) {
  const float* hidden = (const float*)d_in[0];  // [16,512,4096]
  const float* resid  = (const float*)d_in[1];  // [16,512,1024]
  const float* W      = (const float*)d_in[2];  // [1024,4096]
  const float* bias   = (const float*)d_in[3];  // [1024]
  const float* gamma  = (const float*)d_in[4];  // [1024]
  const float* beta   = (const float*)d_in[5];  // [1024]
  float* out = (float*)d_out;                   // [16,512,1024] fp32

  char* ws = (char*)d_ws;
  u16*   Wsgn  = (u16*)ws;                                   // 8 MiB
  float* alpha = (float*)(ws + 8ull * 1024 * 1024);          // 4 KiB

  wprep_kernel<<<N_DIM, 256, 0, stream>>>(W, Wsgn, alpha);

  const int nblocks = (M_DIM / 64) * (N_DIM / 128);  // 1024, 1D swizzled grid
  gemm_kernel<<<nblocks, 256, 0, stream>>>(hidden, Wsgn, alpha, bias, resid, out);

  ln_kernel<<<M_DIM, 256, 0, stream>>>(out, gamma, beta);
}

// Round 4
// 333.166 us; speedup vs baseline: 1.2118x; 1.2118x over previous
//
#include <hip/hip_runtime.h>

using u16    = unsigned short;
using short8 = __attribute__((ext_vector_type(8))) short;
using u16x8  = __attribute__((ext_vector_type(8))) u16;
using u16x4  = __attribute__((ext_vector_type(4))) u16;
using f32x4  = __attribute__((ext_vector_type(4))) float;

#define M_DIM 8192   // B*S = 16*512
#define N_DIM 1024   // D_OUT
#define K_DIM 4096   // D_IN

typedef __attribute__((address_space(1))) void gvoid;
typedef __attribute__((address_space(3))) void svoid;
#define GLOAD_LDS16(g, s) \
  __builtin_amdgcn_global_load_lds((gvoid*)(void*)(g), (svoid*)(s), 16, 0, 0)

__device__ __forceinline__ u16 f2bf(float f) {
  unsigned u = __builtin_bit_cast(unsigned, f);
  u = (u + 0x7FFFu + ((u >> 16) & 1u)) >> 16;   // RNE
  return (u16)u;
}

// ---- kernel 1: per-row alpha = mean|W|, Wsgn = sign(W) as bf16 (+1/-1/0 exact)
__global__ __launch_bounds__(256) void wprep_kernel(const float* __restrict__ W,
                                                    u16* __restrict__ Wsgn,
                                                    float* __restrict__ alpha) {
  const int row = blockIdx.x;
  const int t   = threadIdx.x;
  const float4* wr = (const float4*)(W + (size_t)row * K_DIM);
  float4 v[4];
  float s = 0.f;
#pragma unroll
  for (int j = 0; j < 4; ++j) {
    v[j] = wr[t + 256 * j];
    s += fabsf(v[j].x) + fabsf(v[j].y) + fabsf(v[j].z) + fabsf(v[j].w);
  }
#pragma unroll
  for (int off = 32; off > 0; off >>= 1) s += __shfl_down(s, off, 64);
  __shared__ float red[4];
  if ((t & 63) == 0) red[t >> 6] = s;
  __syncthreads();
  if (t == 0) alpha[row] = (red[0] + red[1] + red[2] + red[3]) * (1.0f / K_DIM);
  u16x4* dst = (u16x4*)(Wsgn + (size_t)row * K_DIM);
#pragma unroll
  for (int j = 0; j < 4; ++j) {
    u16x4 sg;
    sg[0] = v[j].x > 0.f ? 0x3F80 : (v[j].x < 0.f ? 0xBF80 : 0);
    sg[1] = v[j].y > 0.f ? 0x3F80 : (v[j].y < 0.f ? 0xBF80 : 0);
    sg[2] = v[j].z > 0.f ? 0x3F80 : (v[j].z < 0.f ? 0xBF80 : 0);
    sg[3] = v[j].w > 0.f ? 0x3F80 : (v[j].w < 0.f ? 0xBF80 : 0);
    dst[t + 256 * j] = sg;
  }
}

// ---- kernel 2: hidden fp32 -> bf16 (8 elems/thread)
__global__ __launch_bounds__(256) void cast_kernel(const float* __restrict__ in,
                                                   u16* __restrict__ out) {
  const size_t i = ((size_t)blockIdx.x * 256 + threadIdx.x) * 8;
  float4 a = ((const float4*)(in + i))[0];
  float4 b = ((const float4*)(in + i))[1];
  u16x8 p;
  p[0] = f2bf(a.x); p[1] = f2bf(a.y); p[2] = f2bf(a.z); p[3] = f2bf(a.w);
  p[4] = f2bf(b.x); p[5] = f2bf(b.y); p[6] = f2bf(b.z); p[7] = f2bf(b.w);
  *(u16x8*)(out + i) = p;
}

// ---- kernel 3: GEMM C[m,n] = sum_k A[m,k]*Wsgn[n,k], epilogue *alpha + b + resid
// Round 4: r2 structure (128x128, pure-DMA staging, XCD swizzle) with BK=64.
// 64 K-iters (half the barrier/drain epochs), 32 MFMA per wave per epoch.
// LDS layout: [row][64k] rows of 128 B; k-group slot = kg ^ (row&7), folded
// into the per-lane SOURCE address so global_load_lds stays lane-contiguous.
template <bool PRE>
__global__ __launch_bounds__(256) void gemm_kernel(const void* __restrict__ Aopaque,
                                                   const u16* __restrict__ Bsgn,
                                                   const float* __restrict__ alpha,
                                                   const float* __restrict__ bias,
                                                   const float* __restrict__ resid,
                                                   float* __restrict__ out) {
  __shared__ u16 lA[128 * 64];   // 16 KB
  __shared__ u16 lB[128 * 64];   // 16 KB
  const int tid  = threadIdx.x;
  const int wave = tid >> 6;
  const int lane = tid & 63;
  const int quad = lane >> 4;
  const int l16  = lane & 15;
  const int wm   = (wave >> 1) * 64;
  const int wn   = (wave & 1) * 64;

  // XCD swizzle: 512 blocks; xcd = b&7 owns M-bands, all 8 N-tiles per band.
  const int b    = blockIdx.x;
  const int xcd  = b & 7;
  const int l    = b >> 3;                        // 0..63
  const size_t m0 = (size_t)(xcd * 8 + (l >> 3)) * 128;
  const size_t n0 = (size_t)(l & 7) * 128;

  f32x4 acc[4][4] = {};

  // DMA staging: 16 insts per matrix (1 KB each = 8 rows x 128 B), 4/wave.
  // lane -> (row8 = lane>>3, kg = lane&7); source kg xor'd by row8 so that
  // LDS slot s holds logical k-group s ^ (row&7).
  const int r8  = lane >> 3;
  const int kgs = ((lane & 7) ^ r8) * 8;          // source k elem offset
  const u16*   bsrc[4];
  const u16*   asrc16[4];
  u16*         bdst[4];
  u16*         adst[4];
#pragma unroll
  for (int j = 0; j < 4; ++j) {
    const int c = wave * 4 + j;                   // chunk 0..15
    bsrc[j] = Bsgn + (n0 + (size_t)c * 8 + r8) * K_DIM + kgs;
    bdst[j] = lB + c * 512;
    if constexpr (PRE)
      asrc16[j] = (const u16*)Aopaque + (m0 + (size_t)c * 8 + r8) * K_DIM + kgs;
    adst[j] = lA + c * 512;
  }

  for (int k0 = 0; k0 < K_DIM; k0 += 64) {
#pragma unroll
    for (int j = 0; j < 4; ++j) GLOAD_LDS16(bsrc[j] + k0, bdst[j]);
    if constexpr (PRE) {
#pragma unroll
      for (int j = 0; j < 4; ++j) GLOAD_LDS16(asrc16[j] + k0, adst[j]);
    } else {
      // fallback (ws too small): VALU convert, 2 threads per row
      const float* A = (const float*)Aopaque;
      const int row = tid >> 1;
      const int h   = tid & 1;
#pragma unroll
      for (int g = 0; g < 4; ++g) {
        const int kg = h * 4 + g;
        const float4* src = (const float4*)(A + (m0 + row) * (size_t)K_DIM +
                                            k0 + kg * 8);
        float4 f0 = src[0], f1 = src[1];
        u16x8 p;
        p[0] = f2bf(f0.x); p[1] = f2bf(f0.y); p[2] = f2bf(f0.z); p[3] = f2bf(f0.w);
        p[4] = f2bf(f1.x); p[5] = f2bf(f1.y); p[6] = f2bf(f1.z); p[7] = f2bf(f1.w);
        *(u16x8*)(lA + row * 64 + ((kg ^ (row & 7)) * 8)) = p;
      }
    }
    asm volatile("s_waitcnt vmcnt(0)" ::: "memory");
    __syncthreads();

#pragma unroll
    for (int s = 0; s < 2; ++s) {
      short8 af[4], bf[4];
#pragma unroll
      for (int mt = 0; mt < 4; ++mt) {
        const int row = wm + mt * 16 + l16;
        af[mt] = *(const short8*)(lA + row * 64 + (((s * 4 + quad) ^ (row & 7)) * 8));
      }
#pragma unroll
      for (int nt = 0; nt < 4; ++nt) {
        const int col = wn + nt * 16 + l16;
        bf[nt] = *(const short8*)(lB + col * 64 + (((s * 4 + quad) ^ (col & 7)) * 8));
      }
#pragma unroll
      for (int mt = 0; mt < 4; ++mt)
#pragma unroll
        for (int nt = 0; nt < 4; ++nt)
          acc[mt][nt] = __builtin_amdgcn_mfma_f32_16x16x32_bf16(af[mt], bf[nt],
                                                                acc[mt][nt], 0, 0, 0);
    }
    __syncthreads();
  }

  // epilogue: x = acc*alpha[n] + b[n] + resid ; C/D map: col=l16, row=quad*4+r
#pragma unroll
  for (int nt = 0; nt < 4; ++nt) {
    const size_t n  = n0 + wn + nt * 16 + l16;
    const float  al = alpha[n];
    const float  bi = bias[n];
#pragma unroll
    for (int mt = 0; mt < 4; ++mt) {
      const size_t mbase = m0 + wm + mt * 16 + quad * 4;
#pragma unroll
      for (int r = 0; r < 4; ++r) {
        const size_t mm = mbase + r;
        out[mm * N_DIM + n] = acc[mt][nt][r] * al + bi + resid[mm * N_DIM + n];
      }
    }
  }
}

// ---- kernel 4: LayerNorm over last dim (1024), in-place on d_out
__global__ __launch_bounds__(256) void ln_kernel(float* __restrict__ x,
                                                 const float* __restrict__ gamma,
                                                 const float* __restrict__ beta) {
  const size_t row = blockIdx.x;
  float4* xr = (float4*)(x + row * N_DIM);
  const int t = threadIdx.x;
  float4 v = xr[t];
  float s  = v.x + v.y + v.z + v.w;
  float sq = v.x * v.x + v.y * v.y + v.z * v.z + v.w * v.w;
#pragma unroll
  for (int off = 32; off > 0; off >>= 1) {
    s  += __shfl_down(s, off, 64);
    sq += __shfl_down(sq, off, 64);
  }
  __shared__ float rs[4], rq[4];
  if ((t & 63) == 0) { rs[t >> 6] = s; rq[t >> 6] = sq; }
  __syncthreads();
  s  = rs[0] + rs[1] + rs[2] + rs[3];
  sq = rq[0] + rq[1] + rq[2] + rq[3];
  const float mu  = s * (1.0f / N_DIM);
  float var = sq * (1.0f / N_DIM) - mu * mu;
  var = fmaxf(var, 0.0f);
  const float inv = rsqrtf(var + 1e-12f);
  const float4 g = ((const float4*)gamma)[t];
  const float4 b = ((const float4*)beta)[t];
  v.x = g.x * ((v.x - mu) * inv) + b.x;
  v.y = g.y * ((v.y - mu) * inv) + b.y;
  v.z = g.z * ((v.z - mu) * inv) + b.z;
  v.w = g.w * ((v.w - mu) * inv) + b.w;
  xr[t] = v;
}

extern "C" void kernel_launch(void* const* d_in, const int* in_sizes, int n_in,
                              void* d_out, int out_size, void* d_ws, size_t ws_size,
                              hipStream_t stream) {
  const float* hidden = (const float*)d_in[0];  // [16,512,4096]
  const float* resid  = (const float*)d_in[1];  // [16,512,1024]
  const float* W      = (const float*)d_in[2];  // [1024,4096]
  const float* bias   = (const float*)d_in[3];  // [1024]
  const float* gamma  = (const float*)d_in[4];  // [1024]
  const float* beta   = (const float*)d_in[5];  // [1024]
  float* out = (float*)d_out;                   // [16,512,1024] fp32

  char* ws = (char*)d_ws;
  u16*   Wsgn  = (u16*)ws;                                   // 8 MiB
  float* alpha = (float*)(ws + 8ull * 1024 * 1024);          // 4 KiB
  u16*   Abf   = (u16*)(ws + 8ull * 1024 * 1024 + 4096);     // 64 MiB (path A)
  const size_t need_full = 8ull * 1024 * 1024 + 4096 + 64ull * 1024 * 1024;

  wprep_kernel<<<N_DIM, 256, 0, stream>>>(W, Wsgn, alpha);

  const int nblocks = (N_DIM / 128) * (M_DIM / 128);  // 512, 1D swizzled grid
  if (ws_size >= need_full) {
    cast_kernel<<<(M_DIM * (size_t)K_DIM) / (256 * 8), 256, 0, stream>>>(hidden, Abf);
    gemm_kernel<true><<<nblocks, 256, 0, stream>>>((const void*)Abf, Wsgn, alpha,
                                                   bias, resid, out);
  } else {
    gemm_kernel<false><<<nblocks, 256, 0, stream>>>((const void*)hidden, Wsgn, alpha,
                                                    bias, resid, out);
  }
  ln_kernel<<<M_DIM, 256, 0, stream>>>(out, gamma, beta);
}